// Round 8
// baseline (264.227 us; speedup 1.0000x reference)
//
#include <hip/hip_runtime.h>
#include <math.h>

typedef __bf16 bf16_t;
typedef __bf16 v8bf __attribute__((ext_vector_type(8)));
typedef __bf16 v4bf __attribute__((ext_vector_type(4)));
typedef float  v4f  __attribute__((ext_vector_type(4)));

#define AS1 __attribute__((address_space(1)))
#define AS3 __attribute__((address_space(3)))

// async global->LDS 16B copy; LDS dest = wave-uniform base + lane*16
static __device__ __forceinline__ void load_lds16(const bf16_t* g, bf16_t* l) {
    __builtin_amdgcn_global_load_lds((AS1 void*)const_cast<bf16_t*>(g),
                                     (AS3 void*)l, 16, 0, 0);
}

// ---------------------------------------------------------------------------
// Kernel 0: fp32 -> bf16 for h + 4 weights. 8M elems, 8/thread.
// ---------------------------------------------------------------------------
__global__ __launch_bounds__(256) void cvt_fp32_bf16(
    const float* __restrict__ h,  const float* __restrict__ wq,
    const float* __restrict__ wk, const float* __restrict__ wv,
    const float* __restrict__ wo,
    bf16_t* __restrict__ hb,  bf16_t* __restrict__ wqb,
    bf16_t* __restrict__ wkb, bf16_t* __restrict__ wvb,
    bf16_t* __restrict__ wob)
{
    const size_t HM = (size_t)4 << 20;
    const size_t i8 = ((size_t)blockIdx.x * 256 + threadIdx.x) * 8;
    const float* src; bf16_t* dst; size_t off;
    if (i8 < HM) { src = h; dst = hb; off = i8; }
    else {
        const size_t r = (i8 - HM) >> 20;
        off = (i8 - HM) & (((size_t)1 << 20) - 1);
        src = (r == 0) ? wq  : (r == 1) ? wk  : (r == 2) ? wv  : wo;
        dst = (r == 0) ? wqb : (r == 1) ? wkb : (r == 2) ? wvb : wob;
    }
    const float4 a = *(const float4*)(src + off);
    const float4 b = *(const float4*)(src + off + 4);
    v8bf o;
    o[0]=(bf16_t)a.x; o[1]=(bf16_t)a.y; o[2]=(bf16_t)a.z; o[3]=(bf16_t)a.w;
    o[4]=(bf16_t)b.x; o[5]=(bf16_t)b.y; o[6]=(bf16_t)b.z; o[7]=(bf16_t)b.w;
    *(v8bf*)(dst + off) = o;
}

// sin/cos via native HW ops with explicit revolution reduction (no libcall)
static __device__ __forceinline__ void fast_sincos(float ang, float* sn, float* cs) {
    float rv = ang * 0.15915494309189535f;
    rv -= floorf(rv);
    const float a = rv * 6.283185307179586f;
    *sn = __sinf(a);
    *cs = __cosf(a);
}

// ---------------------------------------------------------------------------
// Kernel 1: QKV = h @ [wq|wk|wv]^T, fused RoPE on Q,K. All-bf16 inputs,
// global_load_lds staging. Q,K: [32][2048][64]; V TRANSPOSED: [32][64][2048].
// All epilogue global stores wave-coalesced v8bf via per-wave LDS staging.
// ---------------------------------------------------------------------------
__global__ __launch_bounds__(256) void qkv_gemm_rope(
    const bf16_t* __restrict__ A,   // h bf16 [4096][1024]
    const bf16_t* __restrict__ wq,
    const bf16_t* __restrict__ wk,
    const bf16_t* __restrict__ wv,
    bf16_t* __restrict__ qo, bf16_t* __restrict__ ko, bf16_t* __restrict__ vo)
{
    __shared__ __align__(16) bf16_t smem[17408];
    bf16_t* As = smem;
    bf16_t* Bs = smem + 4096;

    const int tid = threadIdx.x;
    const int n0  = blockIdx.x * 128;
    const int m0  = blockIdx.y * 128;
    const int sel = n0 >> 10;               // 0=Q 1=K 2=V
    const bf16_t* W = (sel == 0) ? wq : (sel == 1) ? wk : wv;
    const int wr0 = n0 & 1023;

    const int wave = tid >> 6;
    const int lane = tid & 63;
    const int l16  = lane & 15;
    const int quad = lane >> 4;
    const int wrow = (wave >> 1) * 64;
    const int wcol = (wave & 1) * 64;

    v4f acc[4][4];
    #pragma unroll
    for (int i = 0; i < 4; ++i)
        #pragma unroll
        for (int j = 0; j < 4; ++j) acc[i][j] = (v4f)(0.0f);

    for (int kt = 0; kt < 32; ++kt) {
        const int k0 = kt * 32;
        #pragma unroll
        for (int rep = 0; rep < 2; ++rep) {
            const int c   = rep * 256 + tid;
            const int row = c >> 2;
            const int col = (c & 3) * 8;
            load_lds16(A + (size_t)(m0 + row) * 1024 + k0 + col, &As[c * 8]);
            load_lds16(W + (size_t)(wr0 + row) * 1024 + k0 + col, &Bs[c * 8]);
        }
        __syncthreads();

        v8bf af[4], bfb[4];
        #pragma unroll
        for (int i = 0; i < 4; ++i) {
            af[i]  = *(const v8bf*)&As[(wrow + i * 16 + l16) * 32 + quad * 8];
            bfb[i] = *(const v8bf*)&Bs[(wcol + i * 16 + l16) * 32 + quad * 8];
        }
        #pragma unroll
        for (int i = 0; i < 4; ++i)
            #pragma unroll
            for (int j = 0; j < 4; ++j)
                acc[i][j] = __builtin_amdgcn_mfma_f32_16x16x32_bf16(
                    af[i], bfb[j], acc[i][j], 0, 0, 0);
        __syncthreads();
    }

    bf16_t* Ls = smem + wave * 4352;          // [64][stride 68]
    const int bq     = (m0 + wrow) >> 11;
    const int hd     = ((n0 + wcol) >> 6) & 15;
    const int t_base = (m0 + wrow) & 2047;

    if (sel < 2) {
        bf16_t* OUT = (sel == 0) ? qo : ko;
        #pragma unroll
        for (int i = 0; i < 4; ++i) {
            #pragma unroll
            for (int j = 0; j < 4; ++j) {
                #pragma unroll
                for (int r = 0; r < 4; ++r) {
                    const int mrow = i * 16 + quad * 4 + r;
                    const int dcol = j * 16 + l16;
                    float v = acc[i][j][r];
                    const float vp = __shfl_xor(v, 1);
                    const int t  = t_base + mrow;
                    const int kk = dcol >> 1;
                    const float freq = exp2f((float)kk * -0.4152410118609203f);
                    float sn, cs;
                    fast_sincos((float)t * freq, &sn, &cs);
                    v = ((dcol & 1) == 0) ? (cs * v - sn * vp) : (sn * vp + cs * v);
                    Ls[mrow * 68 + dcol] = (bf16_t)v;
                }
            }
        }
        #pragma unroll
        for (int s = 0; s < 8; ++s) {
            const int row = s * 8 + (lane >> 3);
            const int off = (lane & 7) * 8;
            const v8bf vv = *(const v8bf*)&Ls[row * 68 + off];
            *(v8bf*)(OUT + (((size_t)(bq * 16 + hd) * 2048) + t_base + row) * 64 + off) = vv;
        }
    } else {
        #pragma unroll
        for (int i = 0; i < 4; ++i)
            #pragma unroll
            for (int j = 0; j < 4; ++j) {
                v4bf p;
                #pragma unroll
                for (int r = 0; r < 4; ++r) p[r] = (bf16_t)acc[i][j][r];
                *(v4bf*)&Ls[(j * 16 + l16) * 68 + i * 16 + quad * 4] = p;
            }
        #pragma unroll
        for (int s = 0; s < 8; ++s) {
            const int drow = s * 8 + (lane >> 3);
            const int off  = (lane & 7) * 8;
            const v8bf vv = *(const v8bf*)&Ls[drow * 68 + off];
            *(v8bf*)(vo + (((size_t)(bq * 16 + hd) * 64) + drow) * 2048 + t_base + off) = vv;
        }
    }
}

// ---------------------------------------------------------------------------
// Kernel 2: causal flash attention, MFMA, S^T orientation, barrier-free.
// One wave (64 thr) per block; wave owns 16 Q rows; paired Q16-tiles
// (127-j, j) -> uniform 33 K-tiles/block. K,V^T fragments loaded DIRECTLY
// from global (L2-hot; XCD-grouped bh so K/V stays in one XCD's L2).
//   S^T = K Q^T : A=K rows (k), B=Q rows (m). C: row=k_loc(quad*4+r), col=m(l16)
//   softmax row m: 16 in-lane vals x 4 lanes -> tree + 2 shfl(16,32)
//   O^T = V^T P^T: A=V^T rows (d), B=P^T (Ps[m][k] contiguous k)
// ---------------------------------------------------------------------------
__global__ __launch_bounds__(64) void attn_mfma(
    const bf16_t* __restrict__ qg,
    const bf16_t* __restrict__ kg,
    const bf16_t* __restrict__ vtg,
    bf16_t* __restrict__ og)
{
    __shared__ __align__(16) bf16_t Ps[16 * 72];   // per-wave P, no barriers

    const int lane = threadIdx.x;
    const int l16  = lane & 15;
    const int quad = lane >> 4;

    const int b0 = blockIdx.x;            // 0..2047
    const int s  = b0 >> 3;               // 0..255
    const int bh = (b0 & 7) * 4 + (s >> 6);   // same-bh blocks -> same XCD slot
    const int jp = s & 63;                // pair index
    const int b  = bh >> 4, hh = bh & 15;

    const bf16_t* Kb = kg  + (size_t)bh * 2048 * 64;
    const bf16_t* Vb = vtg + (size_t)bh * 64 * 2048;

    #pragma unroll
    for (int pass = 0; pass < 2; ++pass) {
        const int q16  = pass ? jp : (127 - jp);
        const int kmax = q16 >> 2;
        const int qglb = q16 * 16 + l16;       // this lane's Q row

        // Q B-frags (row = qglb), fold in 1/8 (exact)
        const bf16_t* qrow = qg + (((size_t)bh * 2048) + qglb) * 64;
        v8bf qf[2];
        qf[0] = *(const v8bf*)(qrow + quad * 8);
        qf[1] = *(const v8bf*)(qrow + 32 + quad * 8);
        #pragma unroll
        for (int e = 0; e < 8; ++e) {
            qf[0][e] = (bf16_t)((float)qf[0][e] * 0.125f);
            qf[1][e] = (bf16_t)((float)qf[1][e] * 0.125f);
        }

        float m_r = -1e30f, l_r = 0.0f;
        v4f o_acc[4];
        #pragma unroll
        for (int d = 0; d < 4; ++d) o_acc[d] = (v4f)(0.0f);

        for (int kt = 0; kt <= kmax; ++kt) {
            // ---- S^T tile: rows k_loc, cols m ----
            v4f s_acc[4];
            #pragma unroll
            for (int kblk = 0; kblk < 4; ++kblk) s_acc[kblk] = (v4f)(0.0f);
            #pragma unroll
            for (int kblk = 0; kblk < 4; ++kblk) {
                const bf16_t* krow = Kb + ((size_t)kt * 64 + kblk * 16 + l16) * 64;
                const v8bf kf0 = *(const v8bf*)(krow + quad * 8);
                const v8bf kf1 = *(const v8bf*)(krow + 32 + quad * 8);
                s_acc[kblk] = __builtin_amdgcn_mfma_f32_16x16x32_bf16(
                    kf0, qf[0], s_acc[kblk], 0, 0, 0);
                s_acc[kblk] = __builtin_amdgcn_mfma_f32_16x16x32_bf16(
                    kf1, qf[1], s_acc[kblk], 0, 0, 0);
            }

            if (kt == kmax) {   // causal mask: k_global > q_global
                #pragma unroll
                for (int kblk = 0; kblk < 4; ++kblk)
                    #pragma unroll
                    for (int r = 0; r < 4; ++r)
                        if (kt * 64 + kblk * 16 + quad * 4 + r > qglb)
                            s_acc[kblk][r] = -1e30f;
            }

            // ---- online softmax: row m=l16 spread over 4 quads x 16 regs ----
            float mx = -1e30f;
            #pragma unroll
            for (int kblk = 0; kblk < 4; ++kblk)
                #pragma unroll
                for (int r = 0; r < 4; ++r) mx = fmaxf(mx, s_acc[kblk][r]);
            mx = fmaxf(mx, __shfl_xor(mx, 16));
            mx = fmaxf(mx, __shfl_xor(mx, 32));
            const float m_new = fmaxf(m_r, mx);
            float ssum = 0.0f;
            #pragma unroll
            for (int kblk = 0; kblk < 4; ++kblk)
                #pragma unroll
                for (int r = 0; r < 4; ++r) {
                    const float p = __expf(s_acc[kblk][r] - m_new);
                    s_acc[kblk][r] = p;
                    ssum += p;
                }
            ssum += __shfl_xor(ssum, 16);
            ssum += __shfl_xor(ssum, 32);
            const float alpha = __expf(m_r - m_new);
            l_r = l_r * alpha + ssum;
            m_r = m_new;

            // ---- P -> Ps[m][k] (v4bf, contiguous k); O^T *= alpha ----
            #pragma unroll
            for (int kblk = 0; kblk < 4; ++kblk) {
                v4bf p;
                #pragma unroll
                for (int r = 0; r < 4; ++r) p[r] = (bf16_t)s_acc[kblk][r];
                *(v4bf*)&Ps[l16 * 72 + kblk * 16 + quad * 4] = p;
            }
            #pragma unroll
            for (int d = 0; d < 4; ++d) o_acc[d] *= alpha;

            // ---- O^T += V^T P^T ----
            v8bf pf0 = *(const v8bf*)&Ps[l16 * 72 + quad * 8];
            v8bf pf1 = *(const v8bf*)&Ps[l16 * 72 + 32 + quad * 8];
            #pragma unroll
            for (int dblk = 0; dblk < 4; ++dblk) {
                const bf16_t* vrow = Vb + ((size_t)(dblk * 16 + l16)) * 2048 + kt * 64;
                const v8bf vf0 = *(const v8bf*)(vrow + quad * 8);
                const v8bf vf1 = *(const v8bf*)(vrow + 32 + quad * 8);
                o_acc[dblk] = __builtin_amdgcn_mfma_f32_16x16x32_bf16(
                    vf0, pf0, o_acc[dblk], 0, 0, 0);
                o_acc[dblk] = __builtin_amdgcn_mfma_f32_16x16x32_bf16(
                    vf1, pf1, o_acc[dblk], 0, 0, 0);
            }
        }

        // ---- epilogue: O^T col m=l16 -> og[b][t][hh*64+d], v4bf stores ----
        const float inv_l = 1.0f / l_r;
        const size_t base = ((size_t)b * 2048 + qglb) * 1024 + hh * 64;
        #pragma unroll
        for (int dblk = 0; dblk < 4; ++dblk) {
            v4bf o;
            #pragma unroll
            for (int r = 0; r < 4; ++r) o[r] = (bf16_t)(o_acc[dblk][r] * inv_l);
            *(v4bf*)(og + base + dblk * 16 + quad * 4) = o;
        }
    }
}

// ---------------------------------------------------------------------------
// Kernel 3: d_out(fp32) = og @ wo^T. Coalesced float2 stores via LDS.
// ---------------------------------------------------------------------------
__global__ __launch_bounds__(256) void out_gemm(
    const bf16_t* __restrict__ A,   // og [4096][1024] bf16
    const bf16_t* __restrict__ W,   // wob [1024][1024] bf16
    float* __restrict__ C)
{
    __shared__ __align__(16) float smemf[8448];
    bf16_t* As = (bf16_t*)smemf;
    bf16_t* Bs = As + 4096;

    const int tid = threadIdx.x;
    const int n0  = blockIdx.x * 128;
    const int m0  = blockIdx.y * 128;

    const int wave = tid >> 6;
    const int lane = tid & 63;
    const int l16  = lane & 15;
    const int quad = lane >> 4;
    const int wrow = (wave >> 1) * 64;
    const int wcol = (wave & 1) * 64;

    v4f acc[4][4];
    #pragma unroll
    for (int i = 0; i < 4; ++i)
        #pragma unroll
        for (int j = 0; j < 4; ++j) acc[i][j] = (v4f)(0.0f);

    for (int kt = 0; kt < 32; ++kt) {
        const int k0 = kt * 32;
        #pragma unroll
        for (int rep = 0; rep < 2; ++rep) {
            const int c   = rep * 256 + tid;
            const int row = c >> 2;
            const int col = (c & 3) * 8;
            load_lds16(A + (size_t)(m0 + row) * 1024 + k0 + col, &As[c * 8]);
            load_lds16(W + (size_t)(n0 + row) * 1024 + k0 + col, &Bs[c * 8]);
        }
        __syncthreads();

        v8bf af[4], bfb[4];
        #pragma unroll
        for (int i = 0; i < 4; ++i) {
            af[i]  = *(const v8bf*)&As[(wrow + i * 16 + l16) * 32 + quad * 8];
            bfb[i] = *(const v8bf*)&Bs[(wcol + i * 16 + l16) * 32 + quad * 8];
        }
        #pragma unroll
        for (int i = 0; i < 4; ++i)
            #pragma unroll
            for (int j = 0; j < 4; ++j)
                acc[i][j] = __builtin_amdgcn_mfma_f32_16x16x32_bf16(
                    af[i], bfb[j], acc[i][j], 0, 0, 0);
        __syncthreads();
    }

    float* Lw = smemf + wave * 2112;
    #pragma unroll
    for (int half = 0; half < 2; ++half) {
        #pragma unroll
        for (int ii = 0; ii < 2; ++ii) {
            const int i = half * 2 + ii;
            #pragma unroll
            for (int j = 0; j < 4; ++j)
                #pragma unroll
                for (int r = 0; r < 4; ++r)
                    Lw[(ii * 16 + quad * 4 + r) * 66 + j * 16 + l16] = acc[i][j][r];
        }
        __syncthreads();
        #pragma unroll
        for (int s = 0; s < 16; ++s) {
            const int row = s * 2 + (lane >> 5);
            const int off = (lane & 31) * 2;
            const float2 vv = *(const float2*)&Lw[row * 66 + off];
            *(float2*)(C + (size_t)(m0 + wrow + half * 32 + row) * 1024 + n0 + wcol + off) = vv;
        }
        __syncthreads();
    }
}

// ---------------------------------------------------------------------------
extern "C" void kernel_launch(void* const* d_in, const int* in_sizes, int n_in,
                              void* d_out, int out_size, void* d_ws, size_t ws_size,
                              hipStream_t stream) {
    const float* h  = (const float*)d_in[0];
    const float* wq = (const float*)d_in[1];
    const float* wk = (const float*)d_in[2];
    const float* wv = (const float*)d_in[3];
    const float* wo = (const float*)d_in[4];

    const size_t NH = (size_t)4096 * 1024;   // 4M
    const size_t NW = (size_t)1024 * 1024;   // 1M

    bf16_t* hb  = (bf16_t*)d_ws;
    bf16_t* wqb = hb  + NH;
    bf16_t* wkb = wqb + NW;
    bf16_t* wvb = wkb + NW;
    bf16_t* wob = wvb + NW;
    bf16_t* qw  = wob + NW;                  // [32][2048][64]
    bf16_t* kw  = qw + NH;
    bf16_t* vw  = kw + NH;                   // [32][64][2048] (V^T)
    bf16_t* og  = hb;                        // alias: hb dead after qkv
    // total: 20M elems = 40 MB

    cvt_fp32_bf16<<<dim3(4096), dim3(256), 0, stream>>>(
        h, wq, wk, wv, wo, hb, wqb, wkb, wvb, wob);
    qkv_gemm_rope<<<dim3(24, 32), dim3(256), 0, stream>>>(hb, wqb, wkb, wvb, qw, kw, vw);
    attn_mfma<<<dim3(2048), dim3(64), 0, stream>>>(qw, kw, vw, og);
    out_gemm<<<dim3(8, 32), dim3(256), 0, stream>>>(og, wob, (float*)d_out);
}

// Round 9
// 189.562 us; speedup vs baseline: 1.3939x; 1.3939x over previous
//
#include <hip/hip_runtime.h>
#include <math.h>

typedef __bf16 bf16_t;
typedef __bf16 v8bf __attribute__((ext_vector_type(8)));
typedef __bf16 v4bf __attribute__((ext_vector_type(4)));
typedef float  v4f  __attribute__((ext_vector_type(4)));

#define AS1 __attribute__((address_space(1)))
#define AS3 __attribute__((address_space(3)))

// async global->LDS 16B copy; LDS dest = wave-uniform base + lane*16
static __device__ __forceinline__ void load_lds16(const bf16_t* g, bf16_t* l) {
    __builtin_amdgcn_global_load_lds((AS1 void*)const_cast<bf16_t*>(g),
                                     (AS3 void*)l, 16, 0, 0);
}

// ---------------------------------------------------------------------------
// Kernel 0: fp32 -> bf16 for h + 4 weights. 8M elems, 8/thread.
// ---------------------------------------------------------------------------
__global__ __launch_bounds__(256) void cvt_fp32_bf16(
    const float* __restrict__ h,  const float* __restrict__ wq,
    const float* __restrict__ wk, const float* __restrict__ wv,
    const float* __restrict__ wo,
    bf16_t* __restrict__ hb,  bf16_t* __restrict__ wqb,
    bf16_t* __restrict__ wkb, bf16_t* __restrict__ wvb,
    bf16_t* __restrict__ wob)
{
    const size_t HM = (size_t)4 << 20;
    const size_t i8 = ((size_t)blockIdx.x * 256 + threadIdx.x) * 8;
    const float* src; bf16_t* dst; size_t off;
    if (i8 < HM) { src = h; dst = hb; off = i8; }
    else {
        const size_t r = (i8 - HM) >> 20;
        off = (i8 - HM) & (((size_t)1 << 20) - 1);
        src = (r == 0) ? wq  : (r == 1) ? wk  : (r == 2) ? wv  : wo;
        dst = (r == 0) ? wqb : (r == 1) ? wkb : (r == 2) ? wvb : wob;
    }
    const float4 a = *(const float4*)(src + off);
    const float4 b = *(const float4*)(src + off + 4);
    v8bf o;
    o[0]=(bf16_t)a.x; o[1]=(bf16_t)a.y; o[2]=(bf16_t)a.z; o[3]=(bf16_t)a.w;
    o[4]=(bf16_t)b.x; o[5]=(bf16_t)b.y; o[6]=(bf16_t)b.z; o[7]=(bf16_t)b.w;
    *(v8bf*)(dst + off) = o;
}

// sin/cos via native HW ops with explicit revolution reduction (no libcall)
static __device__ __forceinline__ void fast_sincos(float ang, float* sn, float* cs) {
    float rv = ang * 0.15915494309189535f;
    rv -= floorf(rv);
    const float a = rv * 6.283185307179586f;
    *sn = __sinf(a);
    *cs = __cosf(a);
}

// ---------------------------------------------------------------------------
// Kernel 1: QKV = h @ [wq|wk|wv]^T, fused RoPE on Q,K. All-bf16 inputs,
// global_load_lds staging. Q,K: [32][2048][64]; V TRANSPOSED: [32][64][2048].
// All epilogue global stores wave-coalesced v8bf via per-wave LDS staging.
// ---------------------------------------------------------------------------
__global__ __launch_bounds__(256) void qkv_gemm_rope(
    const bf16_t* __restrict__ A,   // h bf16 [4096][1024]
    const bf16_t* __restrict__ wq,
    const bf16_t* __restrict__ wk,
    const bf16_t* __restrict__ wv,
    bf16_t* __restrict__ qo, bf16_t* __restrict__ ko, bf16_t* __restrict__ vo)
{
    __shared__ __align__(16) bf16_t smem[17408];
    bf16_t* As = smem;
    bf16_t* Bs = smem + 4096;

    const int tid = threadIdx.x;
    const int n0  = blockIdx.x * 128;
    const int m0  = blockIdx.y * 128;
    const int sel = n0 >> 10;               // 0=Q 1=K 2=V
    const bf16_t* W = (sel == 0) ? wq : (sel == 1) ? wk : wv;
    const int wr0 = n0 & 1023;

    const int wave = tid >> 6;
    const int lane = tid & 63;
    const int l16  = lane & 15;
    const int quad = lane >> 4;
    const int wrow = (wave >> 1) * 64;
    const int wcol = (wave & 1) * 64;

    v4f acc[4][4];
    #pragma unroll
    for (int i = 0; i < 4; ++i)
        #pragma unroll
        for (int j = 0; j < 4; ++j) acc[i][j] = (v4f)(0.0f);

    for (int kt = 0; kt < 32; ++kt) {
        const int k0 = kt * 32;
        #pragma unroll
        for (int rep = 0; rep < 2; ++rep) {
            const int c   = rep * 256 + tid;
            const int row = c >> 2;
            const int col = (c & 3) * 8;
            load_lds16(A + (size_t)(m0 + row) * 1024 + k0 + col, &As[c * 8]);
            load_lds16(W + (size_t)(wr0 + row) * 1024 + k0 + col, &Bs[c * 8]);
        }
        __syncthreads();

        v8bf af[4], bfb[4];
        #pragma unroll
        for (int i = 0; i < 4; ++i) {
            af[i]  = *(const v8bf*)&As[(wrow + i * 16 + l16) * 32 + quad * 8];
            bfb[i] = *(const v8bf*)&Bs[(wcol + i * 16 + l16) * 32 + quad * 8];
        }
        #pragma unroll
        for (int i = 0; i < 4; ++i)
            #pragma unroll
            for (int j = 0; j < 4; ++j)
                acc[i][j] = __builtin_amdgcn_mfma_f32_16x16x32_bf16(
                    af[i], bfb[j], acc[i][j], 0, 0, 0);
        __syncthreads();
    }

    bf16_t* Ls = smem + wave * 4352;          // [64][stride 68]
    const int bq     = (m0 + wrow) >> 11;
    const int hd     = ((n0 + wcol) >> 6) & 15;
    const int t_base = (m0 + wrow) & 2047;

    if (sel < 2) {
        bf16_t* OUT = (sel == 0) ? qo : ko;
        #pragma unroll
        for (int i = 0; i < 4; ++i) {
            #pragma unroll
            for (int j = 0; j < 4; ++j) {
                #pragma unroll
                for (int r = 0; r < 4; ++r) {
                    const int mrow = i * 16 + quad * 4 + r;
                    const int dcol = j * 16 + l16;
                    float v = acc[i][j][r];
                    const float vp = __shfl_xor(v, 1);
                    const int t  = t_base + mrow;
                    const int kk = dcol >> 1;
                    const float freq = exp2f((float)kk * -0.4152410118609203f);
                    float sn, cs;
                    fast_sincos((float)t * freq, &sn, &cs);
                    v = ((dcol & 1) == 0) ? (cs * v - sn * vp) : (sn * vp + cs * v);
                    Ls[mrow * 68 + dcol] = (bf16_t)v;
                }
            }
        }
        #pragma unroll
        for (int s = 0; s < 8; ++s) {
            const int row = s * 8 + (lane >> 3);
            const int off = (lane & 7) * 8;
            const v8bf vv = *(const v8bf*)&Ls[row * 68 + off];
            *(v8bf*)(OUT + (((size_t)(bq * 16 + hd) * 2048) + t_base + row) * 64 + off) = vv;
        }
    } else {
        #pragma unroll
        for (int i = 0; i < 4; ++i)
            #pragma unroll
            for (int j = 0; j < 4; ++j) {
                v4bf p;
                #pragma unroll
                for (int r = 0; r < 4; ++r) p[r] = (bf16_t)acc[i][j][r];
                *(v4bf*)&Ls[(j * 16 + l16) * 68 + i * 16 + quad * 4] = p;
            }
        #pragma unroll
        for (int s = 0; s < 8; ++s) {
            const int drow = s * 8 + (lane >> 3);
            const int off  = (lane & 7) * 8;
            const v8bf vv = *(const v8bf*)&Ls[drow * 68 + off];
            *(v8bf*)(vo + (((size_t)(bq * 16 + hd) * 64) + drow) * 2048 + t_base + off) = vv;
        }
    }
}

// ---------------------------------------------------------------------------
// Kernel 2: causal flash attention — round-7 shell (4 waves, LDS staging,
// register prefetch, paired Q-tiles) + round-8 S^T softmax core (cheap
// in-register row reductions) + XCD-grouped block mapping.
//   Grid: 512 1D blocks; i -> xcd=i&7, pair=(i>>3)&15, g=i>>7;
//   bh = xcd*4+g  => each XCD's 64 blocks serve 4 bh (K+V 2MB < 4MB L2).
//   Per pass (qt = 31-pair, then pair): wave w owns S^T cols m = w*16+l16.
//   S^T = K Q^T (A=K rows from LDS, B=Q rows from regs); softmax per lane:
//   16 in-reg values + shfl_xor(16,32); P -> per-wave LDS (v4bf) -> B-frag;
//   O^T = V^T P^T (A=V^T rows from LDS).
// ---------------------------------------------------------------------------
__global__ __launch_bounds__(256) void attn_mfma(
    const bf16_t* __restrict__ qg,
    const bf16_t* __restrict__ kg,
    const bf16_t* __restrict__ vtg,
    bf16_t* __restrict__ og)
{
    __shared__ __align__(16) bf16_t Ks[64 * 72];
    __shared__ __align__(16) bf16_t Vs[64 * 72];
    __shared__ __align__(16) bf16_t Ps[4][16 * 72];

    const int tid  = threadIdx.x;
    const int wave = tid >> 6;
    const int lane = tid & 63;
    const int l16  = lane & 15;
    const int quad = lane >> 4;

    const int i    = blockIdx.x;            // 0..511
    const int pair = (i >> 3) & 15;         // 0..15
    const int bh   = (i & 7) * 4 + (i >> 7);
    const int b = bh >> 4, hh = bh & 15;

    const bf16_t* Kb = kg  + (size_t)bh * 2048 * 64;
    const bf16_t* Vb = vtg + (size_t)bh * 64 * 2048;

    #pragma unroll
    for (int pass = 0; pass < 2; ++pass) {
        const int qt   = pass ? pair : (31 - pair);
        const int qglb = qt * 64 + wave * 16 + l16;   // this lane's Q row (S^T col)

        // Q B-frags (B operand row = qglb), fold in 1/8 (exact in bf16)
        const bf16_t* qrow = qg + ((size_t)bh * 2048 + qglb) * 64;
        v8bf qf[2];
        qf[0] = *(const v8bf*)(qrow + quad * 8);
        qf[1] = *(const v8bf*)(qrow + 32 + quad * 8);
        #pragma unroll
        for (int e = 0; e < 8; ++e) {
            qf[0][e] = (bf16_t)((float)qf[0][e] * 0.125f);
            qf[1][e] = (bf16_t)((float)qf[1][e] * 0.125f);
        }

        float m_r = -1e30f, l_r = 0.0f;
        v4f o_acc[4];
        #pragma unroll
        for (int d = 0; d < 4; ++d) o_acc[d] = (v4f)(0.0f);

        // prefetch tile 0 into registers (coalesced)
        v8bf kreg[2], vreg[2];
        #pragma unroll
        for (int rep = 0; rep < 2; ++rep) {
            const int c = rep * 256 + tid;
            const int row = c >> 3, col = (c & 7) * 8;
            kreg[rep] = *(const v8bf*)(Kb + (size_t)row * 64 + col);
            vreg[rep] = *(const v8bf*)(Vb + (size_t)row * 2048 + col);
        }

        for (int kt = 0; kt <= qt; ++kt) {
            __syncthreads();   // all waves done reading previous tile's LDS
            #pragma unroll
            for (int rep = 0; rep < 2; ++rep) {
                const int c = rep * 256 + tid;
                const int row = c >> 3, col = (c & 7) * 8;
                *(v8bf*)&Ks[row * 72 + col] = kreg[rep];
                *(v8bf*)&Vs[row * 72 + col] = vreg[rep];
            }
            __syncthreads();

            if (kt < qt) {     // prefetch next tile (latency hidden by compute)
                #pragma unroll
                for (int rep = 0; rep < 2; ++rep) {
                    const int c = rep * 256 + tid;
                    const int row = c >> 3, col = (c & 7) * 8;
                    kreg[rep] = *(const v8bf*)(Kb + ((size_t)(kt + 1) * 64 + row) * 64 + col);
                    vreg[rep] = *(const v8bf*)(Vb + (size_t)row * 2048 + (kt + 1) * 64 + col);
                }
            }

            // ---- S^T tile: rows k_loc, cols m (this wave's 16 Q rows) ----
            v4f s_acc[4];
            #pragma unroll
            for (int kblk = 0; kblk < 4; ++kblk) s_acc[kblk] = (v4f)(0.0f);
            #pragma unroll
            for (int kblk = 0; kblk < 4; ++kblk) {
                const v8bf kf0 = *(const v8bf*)&Ks[(kblk * 16 + l16) * 72 + quad * 8];
                const v8bf kf1 = *(const v8bf*)&Ks[(kblk * 16 + l16) * 72 + 32 + quad * 8];
                s_acc[kblk] = __builtin_amdgcn_mfma_f32_16x16x32_bf16(
                    kf0, qf[0], s_acc[kblk], 0, 0, 0);
                s_acc[kblk] = __builtin_amdgcn_mfma_f32_16x16x32_bf16(
                    kf1, qf[1], s_acc[kblk], 0, 0, 0);
            }

            if (kt == qt) {    // causal mask: k_local > q_local (same 64-tile)
                #pragma unroll
                for (int kblk = 0; kblk < 4; ++kblk)
                    #pragma unroll
                    for (int r = 0; r < 4; ++r)
                        if (kblk * 16 + quad * 4 + r > wave * 16 + l16)
                            s_acc[kblk][r] = -1e30f;
            }

            // ---- online softmax: row m, 16 in-lane vals + 2 shfls ----
            float mx = -1e30f;
            #pragma unroll
            for (int kblk = 0; kblk < 4; ++kblk)
                #pragma unroll
                for (int r = 0; r < 4; ++r) mx = fmaxf(mx, s_acc[kblk][r]);
            mx = fmaxf(mx, __shfl_xor(mx, 16));
            mx = fmaxf(mx, __shfl_xor(mx, 32));
            const float m_new = fmaxf(m_r, mx);
            float ssum = 0.0f;
            #pragma unroll
            for (int kblk = 0; kblk < 4; ++kblk)
                #pragma unroll
                for (int r = 0; r < 4; ++r) {
                    const float p = __expf(s_acc[kblk][r] - m_new);
                    s_acc[kblk][r] = p;
                    ssum += p;
                }
            ssum += __shfl_xor(ssum, 16);
            ssum += __shfl_xor(ssum, 32);
            const float alpha = __expf(m_r - m_new);
            l_r = l_r * alpha + ssum;
            m_r = m_new;

            // ---- P -> Ps[wave][m=l16][k] (v4bf contiguous k); O^T *= alpha --
            #pragma unroll
            for (int kblk = 0; kblk < 4; ++kblk) {
                v4bf p;
                #pragma unroll
                for (int r = 0; r < 4; ++r) p[r] = (bf16_t)s_acc[kblk][r];
                *(v4bf*)&Ps[wave][l16 * 72 + kblk * 16 + quad * 4] = p;
            }
            #pragma unroll
            for (int d = 0; d < 4; ++d) o_acc[d] *= alpha;

            // ---- O^T += V^T P^T (same-wave LDS RAW: in-order DS pipe) ----
            const v8bf pf0 = *(const v8bf*)&Ps[wave][l16 * 72 + quad * 8];
            const v8bf pf1 = *(const v8bf*)&Ps[wave][l16 * 72 + 32 + quad * 8];
            #pragma unroll
            for (int dblk = 0; dblk < 4; ++dblk) {
                const v8bf vf0 = *(const v8bf*)&Vs[(dblk * 16 + l16) * 72 + quad * 8];
                const v8bf vf1 = *(const v8bf*)&Vs[(dblk * 16 + l16) * 72 + 32 + quad * 8];
                o_acc[dblk] = __builtin_amdgcn_mfma_f32_16x16x32_bf16(
                    vf0, pf0, o_acc[dblk], 0, 0, 0);
                o_acc[dblk] = __builtin_amdgcn_mfma_f32_16x16x32_bf16(
                    vf1, pf1, o_acc[dblk], 0, 0, 0);
            }
        }

        // ---- epilogue: O^T col m=l16 -> og[b][t][hh*64+d], v4bf stores ----
        const float inv_l = 1.0f / l_r;
        const size_t base = ((size_t)b * 2048 + qglb) * 1024 + hh * 64;
        #pragma unroll
        for (int dblk = 0; dblk < 4; ++dblk) {
            v4bf o;
            #pragma unroll
            for (int r = 0; r < 4; ++r) o[r] = (bf16_t)(o_acc[dblk][r] * inv_l);
            *(v4bf*)(og + base + dblk * 16 + quad * 4) = o;
        }
    }
}

// ---------------------------------------------------------------------------
// Kernel 3: d_out(fp32) = og @ wo^T. Coalesced float2 stores via LDS.
// ---------------------------------------------------------------------------
__global__ __launch_bounds__(256) void out_gemm(
    const bf16_t* __restrict__ A,   // og [4096][1024] bf16
    const bf16_t* __restrict__ W,   // wob [1024][1024] bf16
    float* __restrict__ C)
{
    __shared__ __align__(16) float smemf[8448];
    bf16_t* As = (bf16_t*)smemf;
    bf16_t* Bs = As + 4096;

    const int tid = threadIdx.x;
    const int n0  = blockIdx.x * 128;
    const int m0  = blockIdx.y * 128;

    const int wave = tid >> 6;
    const int lane = tid & 63;
    const int l16  = lane & 15;
    const int quad = lane >> 4;
    const int wrow = (wave >> 1) * 64;
    const int wcol = (wave & 1) * 64;

    v4f acc[4][4];
    #pragma unroll
    for (int i = 0; i < 4; ++i)
        #pragma unroll
        for (int j = 0; j < 4; ++j) acc[i][j] = (v4f)(0.0f);

    for (int kt = 0; kt < 32; ++kt) {
        const int k0 = kt * 32;
        #pragma unroll
        for (int rep = 0; rep < 2; ++rep) {
            const int c   = rep * 256 + tid;
            const int row = c >> 2;
            const int col = (c & 3) * 8;
            load_lds16(A + (size_t)(m0 + row) * 1024 + k0 + col, &As[c * 8]);
            load_lds16(W + (size_t)(n0 + row) * 1024 + k0 + col, &Bs[c * 8]);
        }
        __syncthreads();

        v8bf af[4], bfb[4];
        #pragma unroll
        for (int i = 0; i < 4; ++i) {
            af[i]  = *(const v8bf*)&As[(wrow + i * 16 + l16) * 32 + quad * 8];
            bfb[i] = *(const v8bf*)&Bs[(wcol + i * 16 + l16) * 32 + quad * 8];
        }
        #pragma unroll
        for (int i = 0; i < 4; ++i)
            #pragma unroll
            for (int j = 0; j < 4; ++j)
                acc[i][j] = __builtin_amdgcn_mfma_f32_16x16x32_bf16(
                    af[i], bfb[j], acc[i][j], 0, 0, 0);
        __syncthreads();
    }

    float* Lw = smemf + wave * 2112;
    #pragma unroll
    for (int half = 0; half < 2; ++half) {
        #pragma unroll
        for (int ii = 0; ii < 2; ++ii) {
            const int i = half * 2 + ii;
            #pragma unroll
            for (int j = 0; j < 4; ++j)
                #pragma unroll
                for (int r = 0; r < 4; ++r)
                    Lw[(ii * 16 + quad * 4 + r) * 66 + j * 16 + l16] = acc[i][j][r];
        }
        __syncthreads();
        #pragma unroll
        for (int s = 0; s < 16; ++s) {
            const int row = s * 2 + (lane >> 5);
            const int off = (lane & 31) * 2;
            const float2 vv = *(const float2*)&Lw[row * 66 + off];
            *(float2*)(C + (size_t)(m0 + wrow + half * 32 + row) * 1024 + n0 + wcol + off) = vv;
        }
        __syncthreads();
    }
}

// ---------------------------------------------------------------------------
extern "C" void kernel_launch(void* const* d_in, const int* in_sizes, int n_in,
                              void* d_out, int out_size, void* d_ws, size_t ws_size,
                              hipStream_t stream) {
    const float* h  = (const float*)d_in[0];
    const float* wq = (const float*)d_in[1];
    const float* wk = (const float*)d_in[2];
    const float* wv = (const float*)d_in[3];
    const float* wo = (const float*)d_in[4];

    const size_t NH = (size_t)4096 * 1024;   // 4M
    const size_t NW = (size_t)1024 * 1024;   // 1M

    bf16_t* hb  = (bf16_t*)d_ws;
    bf16_t* wqb = hb  + NH;
    bf16_t* wkb = wqb + NW;
    bf16_t* wvb = wkb + NW;
    bf16_t* wvv = wvb;  // (unused alias, keep naming clear)
    bf16_t* wob = wvb + NW;
    bf16_t* qw  = wob + NW;                  // [32][2048][64]
    bf16_t* kw  = qw + NH;
    bf16_t* vw  = kw + NH;                   // [32][64][2048] (V^T)
    bf16_t* og  = hb;                        // alias: hb dead after qkv
    (void)wvv;
    // total: 20M elems = 40 MB

    cvt_fp32_bf16<<<dim3(4096), dim3(256), 0, stream>>>(
        h, wq, wk, wv, wo, hb, wqb, wkb, wvb, wob);
    qkv_gemm_rope<<<dim3(24, 32), dim3(256), 0, stream>>>(hb, wqb, wkb, wvb, qw, kw, vw);
    attn_mfma<<<dim3(512), dim3(256), 0, stream>>>(qw, kw, vw, og);
    out_gemm<<<dim3(8, 32), dim3(256), 0, stream>>>(og, wob, (float*)d_out);
}